// Round 2
// baseline (3354.170 us; speedup 1.0000x reference)
//
#include <hip/hip_runtime.h>
#include <math.h>

#define N_NODES 100000
#define IN_DIM  128
#define HIDDEN  64
#define N_EDGES 1600000

// ---------------------------------------------------------------------------
// Kernel 0: zero the readout accumulator (aliases d_out, poisoned by harness).
// ---------------------------------------------------------------------------
__global__ __launch_bounds__(256) void zero_kernel(float4* __restrict__ p, int n4)
{
    const int i = blockIdx.x * 256 + threadIdx.x;
    if (i < n4) p[i] = make_float4(0.f, 0.f, 0.f, 0.f);
}

// ---------------------------------------------------------------------------
// Kernel 1: per-node gate  w[i] = sigmoid(tanh(x_i @ W_sim + b_sim) @ w_vec + b_vec)
// One wave (64 lanes) per node; lane j owns hidden unit j.
// ---------------------------------------------------------------------------
__global__ __launch_bounds__(256) void gate_kernel(
    const float* __restrict__ x, const float* __restrict__ W_sim,
    const float* __restrict__ b_sim, const float* __restrict__ w_vec,
    const float* __restrict__ b_vec, float* __restrict__ weights)
{
    __shared__ float sW[IN_DIM * HIDDEN]; // 32 KB
    for (int i = threadIdx.x; i < IN_DIM * HIDDEN; i += 256) sW[i] = W_sim[i];
    __syncthreads();

    const int wave = threadIdx.x >> 6;
    const int lane = threadIdx.x & 63;
    const int node = blockIdx.x * 4 + wave;
    if (node >= N_NODES) return;

    const float* xr = x + (size_t)node * IN_DIM;
    float acc = 0.f;
#pragma unroll 4
    for (int k = 0; k < IN_DIM; ++k)
        acc += xr[k] * sW[k * HIDDEN + lane];   // bank = lane%32 -> 2-way (free)

    float c = tanhf(acc + b_sim[lane]) * w_vec[lane];
    // wave64 reduction
#pragma unroll
    for (int off = 32; off > 0; off >>= 1)
        c += __shfl_down(c, off, 64);

    if (lane == 0) {
        float z = c + b_vec[0];
        weights[node] = 1.f / (1.f + expf(-z));
    }
}

// ---------------------------------------------------------------------------
// Kernel 2: edge scatter  readout[row] += x[col] * w[col]
// One thread per (edge, 4-float chunk): 32 threads cover one edge's 128 floats,
// so the x-row gather is a coalesced 512B burst per half-wave.
// readout aliases d_out (zeroed by zero_kernel); fp32 global atomics.
// NOTE: edge_index arrives as int32 (JAX x64 disabled downcasts int64).
// ---------------------------------------------------------------------------
__global__ __launch_bounds__(256) void scatter_kernel(
    const float* __restrict__ x, const int* __restrict__ edge_index,
    const float* __restrict__ weights, float* __restrict__ readout)
{
    const int gid = blockIdx.x * 256 + threadIdx.x;
    const int e = gid >> 5;
    const int c = gid & 31;
    if (e >= N_EDGES) return;

    const int row = edge_index[e];            // same addr across 32 lanes -> broadcast
    const int col = edge_index[N_EDGES + e];
    const float w = weights[col];

    const float4 xv = ((const float4*)(x + (size_t)col * IN_DIM))[c];
    float* dst = readout + (size_t)row * IN_DIM + c * 4;
    atomicAdd(dst + 0, xv.x * w);
    atomicAdd(dst + 1, xv.y * w);
    atomicAdd(dst + 2, xv.z * w);
    atomicAdd(dst + 3, xv.w * w);
}

// ---------------------------------------------------------------------------
// Kernel 3: prompts = relu(readout @ W1 + b1) @ W2 + b2 ; out = x + prompts
// One wave per node. readout aliases out: each wave reads its full row into
// the k-loop before writing that row, so in-place is safe.
// ---------------------------------------------------------------------------
__global__ __launch_bounds__(256) void prompt_kernel(
    const float* __restrict__ x, float* __restrict__ out /* = readout in */,
    const float* __restrict__ W1, const float* __restrict__ b1,
    const float* __restrict__ W2, const float* __restrict__ b2)
{
    __shared__ float sW1[IN_DIM * HIDDEN]; // 32 KB
    __shared__ float sW2[HIDDEN * IN_DIM]; // 32 KB
    __shared__ float sH[4][HIDDEN];        // 1 KB
    for (int i = threadIdx.x; i < IN_DIM * HIDDEN; i += 256) {
        sW1[i] = W1[i];
        sW2[i] = W2[i];
    }
    __syncthreads();

    const int wave = threadIdx.x >> 6;
    const int lane = threadIdx.x & 63;
    const int node = blockIdx.x * 4 + wave;
    if (node >= N_NODES) return;

    const float* rr = out + (size_t)node * IN_DIM;  // readout row (accumulated)
    float acc = 0.f;
#pragma unroll 4
    for (int k = 0; k < IN_DIM; ++k)
        acc += rr[k] * sW1[k * HIDDEN + lane];

    sH[wave][lane] = fmaxf(acc + b1[lane], 0.f);
    __syncthreads();

    float o0 = b2[lane];
    float o1 = b2[64 + lane];
#pragma unroll 4
    for (int j = 0; j < HIDDEN; ++j) {
        const float hj = sH[wave][j];
        o0 += hj * sW2[j * IN_DIM + lane];
        o1 += hj * sW2[j * IN_DIM + 64 + lane];
    }
    const size_t base = (size_t)node * IN_DIM;
    out[base + lane]      = x[base + lane]      + o0;
    out[base + 64 + lane] = x[base + 64 + lane] + o1;
}

// ---------------------------------------------------------------------------
extern "C" void kernel_launch(void* const* d_in, const int* in_sizes, int n_in,
                              void* d_out, int out_size, void* d_ws, size_t ws_size,
                              hipStream_t stream)
{
    const float* x          = (const float*)d_in[0];
    const int*   edge_index = (const int*)d_in[1];   // int32 per harness convention
    const float* W_sim      = (const float*)d_in[2];
    const float* b_sim      = (const float*)d_in[3];
    const float* w_vec      = (const float*)d_in[4];
    const float* b_vec      = (const float*)d_in[5];
    const float* W1         = (const float*)d_in[6];
    const float* b1         = (const float*)d_in[7];
    const float* W2         = (const float*)d_in[8];
    const float* b2         = (const float*)d_in[9];

    float* out     = (float*)d_out;
    float* weights = (float*)d_ws;   // N_NODES floats (400 KB)

    const int n4 = N_NODES * IN_DIM / 4;  // 3.2M float4
    zero_kernel<<<(n4 + 255) / 256, 256, 0, stream>>>((float4*)out, n4);

    gate_kernel<<<N_NODES / 4, 256, 0, stream>>>(x, W_sim, b_sim, w_vec, b_vec, weights);

    const int scatter_threads = N_EDGES * 32;
    scatter_kernel<<<scatter_threads / 256, 256, 0, stream>>>(x, edge_index, weights, out);

    prompt_kernel<<<N_NODES / 4, 256, 0, stream>>>(x, out, W1, b1, W2, b2);
}

// Round 3
// 976.702 us; speedup vs baseline: 3.4342x; 3.4342x over previous
//
#include <hip/hip_runtime.h>
#include <math.h>

#define N_NODES 100000
#define IN_DIM  128
#define HIDDEN  64
#define N_EDGES 1600000

// ---------------------------------------------------------------------------
// Workspace layout (4-byte units):
//   [0,       100000)   weights  (float)  per-node gate
//   [100000,  200000)   counts   (int)    per-node in-degree
//   [200000,  300000)   cursor   (int)    per-node fill cursor
//   [300000,  300016)   counter  (int)    global bump allocator
//   [300016,  400016)   base     (int)    per-node segment base in bucket
//   [400016, 2000016)   bucket   (int)    edge source (col) grouped by row
// Total: 8.0 MB
// ---------------------------------------------------------------------------
#define WS_WEIGHTS 0
#define WS_COUNTS  100000
#define WS_CURSOR  200000
#define WS_COUNTER 300000
#define WS_BASE    300016
#define WS_BUCKET  400016
#define WS_TOTAL   2000016

// ---------------------------------------------------------------------------
__global__ __launch_bounds__(256) void zero_int_kernel(int* __restrict__ p, int n)
{
    const int i = blockIdx.x * 256 + threadIdx.x;
    if (i < n) p[i] = 0;
}

__global__ __launch_bounds__(256) void zero_f4_kernel(float4* __restrict__ p, int n4)
{
    const int i = blockIdx.x * 256 + threadIdx.x;
    if (i < n4) p[i] = make_float4(0.f, 0.f, 0.f, 0.f);
}

// ---------------------------------------------------------------------------
// Gate: w[i] = sigmoid(tanh(x_i @ W_sim + b_sim) @ w_vec + b_vec). Wave/node.
// ---------------------------------------------------------------------------
__global__ __launch_bounds__(256) void gate_kernel(
    const float* __restrict__ x, const float* __restrict__ W_sim,
    const float* __restrict__ b_sim, const float* __restrict__ w_vec,
    const float* __restrict__ b_vec, float* __restrict__ weights)
{
    __shared__ float sW[IN_DIM * HIDDEN]; // 32 KB
    for (int i = threadIdx.x; i < IN_DIM * HIDDEN; i += 256) sW[i] = W_sim[i];
    __syncthreads();

    const int wave = threadIdx.x >> 6;
    const int lane = threadIdx.x & 63;
    const int node = blockIdx.x * 4 + wave;
    if (node >= N_NODES) return;

    const float* xr = x + (size_t)node * IN_DIM;
    float acc = 0.f;
#pragma unroll 4
    for (int k = 0; k < IN_DIM; ++k)
        acc += xr[k] * sW[k * HIDDEN + lane];

    float c = tanhf(acc + b_sim[lane]) * w_vec[lane];
#pragma unroll
    for (int off = 32; off > 0; off >>= 1)
        c += __shfl_down(c, off, 64);

    if (lane == 0)
        weights[node] = 1.f / (1.f + expf(-(c + b_vec[0])));
}

// ---------------------------------------------------------------------------
// Binning step 1: in-degree histogram.
// ---------------------------------------------------------------------------
__global__ __launch_bounds__(256) void hist_kernel(
    const int* __restrict__ edge_index, int* __restrict__ counts)
{
    const int e = blockIdx.x * 256 + threadIdx.x;
    if (e < N_EDGES) atomicAdd(&counts[edge_index[e]], 1);
}

// ---------------------------------------------------------------------------
// Binning step 2: per-node segment base via wave-scan + one atomic per wave.
// Segments are contiguous per node; global order is irrelevant.
// ---------------------------------------------------------------------------
__global__ __launch_bounds__(256) void alloc_kernel(
    const int* __restrict__ counts, int* __restrict__ base, int* __restrict__ counter)
{
    const int node = blockIdx.x * 256 + threadIdx.x;
    const int lane = threadIdx.x & 63;
    const int c = (node < N_NODES) ? counts[node] : 0;

    int incl = c;
#pragma unroll
    for (int off = 1; off < 64; off <<= 1) {
        int v = __shfl_up(incl, off, 64);
        if (lane >= off) incl += v;
    }
    const int excl = incl - c;
    int wbase = 0;
    if (lane == 63) wbase = atomicAdd(counter, incl);
    wbase = __shfl(wbase, 63, 64);

    if (node < N_NODES) base[node] = wbase + excl;
}

// ---------------------------------------------------------------------------
// Binning step 3: scatter edge sources into their destination's segment.
// ---------------------------------------------------------------------------
__global__ __launch_bounds__(256) void fill_kernel(
    const int* __restrict__ edge_index, const int* __restrict__ base,
    int* __restrict__ cursor, int* __restrict__ bucket)
{
    const int e = blockIdx.x * 256 + threadIdx.x;
    if (e >= N_EDGES) return;
    const int row = edge_index[e];
    const int col = edge_index[N_EDGES + e];
    const int pos = atomicAdd(&cursor[row], 1);
    bucket[base[row] + pos] = col;
}

// ---------------------------------------------------------------------------
// Gather-accumulate: one wave per destination node; readout row written once.
// ---------------------------------------------------------------------------
__global__ __launch_bounds__(256) void gather_kernel(
    const float* __restrict__ x, const float* __restrict__ weights,
    const int* __restrict__ counts, const int* __restrict__ base,
    const int* __restrict__ bucket, float* __restrict__ readout)
{
    const int wave = threadIdx.x >> 6;
    const int lane = threadIdx.x & 63;
    const int node = blockIdx.x * 4 + wave;
    if (node >= N_NODES) return;

    const int m = counts[node];
    const int b = base[node];

    float2 acc = make_float2(0.f, 0.f);
    for (int i = 0; i < m; ++i) {
        const int col = bucket[b + i];          // wave-uniform -> scalar load
        const float w = weights[col];
        const float2 xv = ((const float2*)(x + (size_t)col * IN_DIM))[lane];
        acc.x += xv.x * w;
        acc.y += xv.y * w;
    }
    ((float2*)(readout + (size_t)node * IN_DIM))[lane] = acc;
}

// ---------------------------------------------------------------------------
// Fallback scatter (atomic) — used only if ws_size is too small for binning.
// ---------------------------------------------------------------------------
__global__ __launch_bounds__(256) void scatter_kernel(
    const float* __restrict__ x, const int* __restrict__ edge_index,
    const float* __restrict__ weights, float* __restrict__ readout)
{
    const int gid = blockIdx.x * 256 + threadIdx.x;
    const int e = gid >> 5;
    const int c = gid & 31;
    if (e >= N_EDGES) return;
    const int row = edge_index[e];
    const int col = edge_index[N_EDGES + e];
    const float w = weights[col];
    const float4 xv = ((const float4*)(x + (size_t)col * IN_DIM))[c];
    float* dst = readout + (size_t)row * IN_DIM + c * 4;
    atomicAdd(dst + 0, xv.x * w);
    atomicAdd(dst + 1, xv.y * w);
    atomicAdd(dst + 2, xv.z * w);
    atomicAdd(dst + 3, xv.w * w);
}

// ---------------------------------------------------------------------------
// Prompt MLP: out = x + relu(readout@W1+b1)@W2 + b2. Wave/node, in-place on out.
// ---------------------------------------------------------------------------
__global__ __launch_bounds__(256) void prompt_kernel(
    const float* __restrict__ x, float* __restrict__ out /* = readout */,
    const float* __restrict__ W1, const float* __restrict__ b1,
    const float* __restrict__ W2, const float* __restrict__ b2)
{
    __shared__ float sW1[IN_DIM * HIDDEN]; // 32 KB
    __shared__ float sW2[HIDDEN * IN_DIM]; // 32 KB
    __shared__ float sH[4][HIDDEN];
    for (int i = threadIdx.x; i < IN_DIM * HIDDEN; i += 256) {
        sW1[i] = W1[i];
        sW2[i] = W2[i];
    }
    __syncthreads();

    const int wave = threadIdx.x >> 6;
    const int lane = threadIdx.x & 63;
    const int node = blockIdx.x * 4 + wave;
    if (node >= N_NODES) return;

    const float* rr = out + (size_t)node * IN_DIM;
    float acc = 0.f;
#pragma unroll 4
    for (int k = 0; k < IN_DIM; ++k)
        acc += rr[k] * sW1[k * HIDDEN + lane];

    sH[wave][lane] = fmaxf(acc + b1[lane], 0.f);
    __syncthreads();

    float o0 = b2[lane];
    float o1 = b2[64 + lane];
#pragma unroll 4
    for (int j = 0; j < HIDDEN; ++j) {
        const float hj = sH[wave][j];
        o0 += hj * sW2[j * IN_DIM + lane];
        o1 += hj * sW2[j * IN_DIM + 64 + lane];
    }
    const size_t bidx = (size_t)node * IN_DIM;
    out[bidx + lane]      = x[bidx + lane]      + o0;
    out[bidx + 64 + lane] = x[bidx + 64 + lane] + o1;
}

// ---------------------------------------------------------------------------
extern "C" void kernel_launch(void* const* d_in, const int* in_sizes, int n_in,
                              void* d_out, int out_size, void* d_ws, size_t ws_size,
                              hipStream_t stream)
{
    const float* x          = (const float*)d_in[0];
    const int*   edge_index = (const int*)d_in[1];   // int32 (JAX x64 disabled)
    const float* W_sim      = (const float*)d_in[2];
    const float* b_sim      = (const float*)d_in[3];
    const float* w_vec      = (const float*)d_in[4];
    const float* b_vec      = (const float*)d_in[5];
    const float* W1         = (const float*)d_in[6];
    const float* b1         = (const float*)d_in[7];
    const float* W2         = (const float*)d_in[8];
    const float* b2         = (const float*)d_in[9];

    float* out = (float*)d_out;
    float* wsf = (float*)d_ws;
    int*   wsi = (int*)d_ws;

    float* weights = wsf + WS_WEIGHTS;

    gate_kernel<<<N_NODES / 4, 256, 0, stream>>>(x, W_sim, b_sim, w_vec, b_vec, weights);

    if (ws_size >= (size_t)WS_TOTAL * 4) {
        int* counts  = wsi + WS_COUNTS;
        int* cursor  = wsi + WS_CURSOR;
        int* counter = wsi + WS_COUNTER;
        int* base    = wsi + WS_BASE;
        int* bucket  = wsi + WS_BUCKET;

        // zero counts+cursor+counter in one contiguous sweep
        const int nz = WS_BASE - WS_COUNTS;  // 200016 ints
        zero_int_kernel<<<(nz + 255) / 256, 256, 0, stream>>>(wsi + WS_COUNTS, nz);

        hist_kernel<<<(N_EDGES + 255) / 256, 256, 0, stream>>>(edge_index, counts);
        alloc_kernel<<<(N_NODES + 255) / 256, 256, 0, stream>>>(counts, base, counter);
        fill_kernel<<<(N_EDGES + 255) / 256, 256, 0, stream>>>(edge_index, base, cursor, bucket);
        gather_kernel<<<N_NODES / 4, 256, 0, stream>>>(x, weights, counts, base, bucket, out);
    } else {
        // fallback: atomic scatter into zeroed out
        const int n4 = N_NODES * IN_DIM / 4;
        zero_f4_kernel<<<(n4 + 255) / 256, 256, 0, stream>>>((float4*)out, n4);
        scatter_kernel<<<(N_EDGES * 32) / 256, 256, 0, stream>>>(x, edge_index, weights, out);
    }

    prompt_kernel<<<N_NODES / 4, 256, 0, stream>>>(x, out, W1, b1, W2, b2);
}

// Round 4
// 665.522 us; speedup vs baseline: 5.0399x; 1.4676x over previous
//
#include <hip/hip_runtime.h>
#include <math.h>

#define N_NODES 100000
#define IN_DIM  128
#define HIDDEN  64
#define N_EDGES 1600000

// ---------------------------------------------------------------------------
// Workspace layout (4-byte units):
//   [0,       100000)   weights  (float)  per-node gate
//   [100000,  200000)   counts   (int)    per-node in-degree
//   [200000,  300000)   cursor   (int)    per-node fill cursor
//   [300000,  300016)   counter  (int)    global bump allocator
//   [300016,  400016)   base     (int)    per-node segment base in bucket
//   [400016, 2000016)   bucket   (int)    edge source (col) grouped by row
// ---------------------------------------------------------------------------
#define WS_WEIGHTS 0
#define WS_COUNTS  100000
#define WS_CURSOR  200000
#define WS_COUNTER 300000
#define WS_BASE    300016
#define WS_BUCKET  400016
#define WS_TOTAL   2000016

__global__ __launch_bounds__(256) void zero_int_kernel(int* __restrict__ p, int n)
{
    const int i = blockIdx.x * 256 + threadIdx.x;
    if (i < n) p[i] = 0;
}

__global__ __launch_bounds__(256) void zero_f4_kernel(float4* __restrict__ p, int n4)
{
    const int i = blockIdx.x * 256 + threadIdx.x;
    if (i < n4) p[i] = make_float4(0.f, 0.f, 0.f, 0.f);
}

// ---------------------------------------------------------------------------
// Gate v3: one THREAD per node. Weight indices are wave-uniform -> compiler
// scalar-loads W_sim rows into SGPRs; v_fmac takes the SGPR operand directly.
// No LDS, no barriers. j chunked by 16 to bound live SGPRs.
// ---------------------------------------------------------------------------
__global__ __launch_bounds__(256) void gate_kernel(
    const float* __restrict__ x, const float* __restrict__ W_sim,
    const float* __restrict__ b_sim, const float* __restrict__ w_vec,
    const float* __restrict__ b_vec, float* __restrict__ weights)
{
    const int node = blockIdx.x * 256 + threadIdx.x;
    if (node >= N_NODES) return;
    const float4* xr = (const float4*)(x + (size_t)node * IN_DIM);

    float g = 0.f;
    for (int jc = 0; jc < HIDDEN; jc += 16) {
        float acc[16];
#pragma unroll
        for (int jj = 0; jj < 16; ++jj) acc[jj] = b_sim[jc + jj];
        for (int k4 = 0; k4 < IN_DIM / 4; ++k4) {
            const float4 a = xr[k4];
#pragma unroll
            for (int jj = 0; jj < 16; ++jj) {
                acc[jj] += a.x * W_sim[(4 * k4 + 0) * HIDDEN + jc + jj];
                acc[jj] += a.y * W_sim[(4 * k4 + 1) * HIDDEN + jc + jj];
                acc[jj] += a.z * W_sim[(4 * k4 + 2) * HIDDEN + jc + jj];
                acc[jj] += a.w * W_sim[(4 * k4 + 3) * HIDDEN + jc + jj];
            }
        }
#pragma unroll
        for (int jj = 0; jj < 16; ++jj)
            g += tanhf(acc[jj]) * w_vec[jc + jj];
    }
    weights[node] = 1.f / (1.f + expf(-(g + b_vec[0])));
}

// ---------------------------------------------------------------------------
// Binning: histogram -> segment alloc -> bucket fill (unchanged from R3).
// ---------------------------------------------------------------------------
__global__ __launch_bounds__(256) void hist_kernel(
    const int* __restrict__ edge_index, int* __restrict__ counts)
{
    const int e = blockIdx.x * 256 + threadIdx.x;
    if (e < N_EDGES) atomicAdd(&counts[edge_index[e]], 1);
}

__global__ __launch_bounds__(256) void alloc_kernel(
    const int* __restrict__ counts, int* __restrict__ base, int* __restrict__ counter)
{
    const int node = blockIdx.x * 256 + threadIdx.x;
    const int lane = threadIdx.x & 63;
    const int c = (node < N_NODES) ? counts[node] : 0;

    int incl = c;
#pragma unroll
    for (int off = 1; off < 64; off <<= 1) {
        int v = __shfl_up(incl, off, 64);
        if (lane >= off) incl += v;
    }
    const int excl = incl - c;
    int wbase = 0;
    if (lane == 63) wbase = atomicAdd(counter, incl);
    wbase = __shfl(wbase, 63, 64);

    if (node < N_NODES) base[node] = wbase + excl;
}

__global__ __launch_bounds__(256) void fill_kernel(
    const int* __restrict__ edge_index, const int* __restrict__ base,
    int* __restrict__ cursor, int* __restrict__ bucket)
{
    const int e = blockIdx.x * 256 + threadIdx.x;
    if (e >= N_EDGES) return;
    const int row = edge_index[e];
    const int col = edge_index[N_EDGES + e];
    const int pos = atomicAdd(&cursor[row], 1);
    bucket[base[row] + pos] = col;
}

// ---------------------------------------------------------------------------
// Gather-accumulate: one wave per destination node; row written once.
// ---------------------------------------------------------------------------
__global__ __launch_bounds__(256) void gather_kernel(
    const float* __restrict__ x, const float* __restrict__ weights,
    const int* __restrict__ counts, const int* __restrict__ base,
    const int* __restrict__ bucket, float* __restrict__ readout)
{
    const int wave = threadIdx.x >> 6;
    const int lane = threadIdx.x & 63;
    const int node = blockIdx.x * 4 + wave;
    if (node >= N_NODES) return;

    const int m = counts[node];
    const int b = base[node];

    float2 acc = make_float2(0.f, 0.f);
    for (int i = 0; i < m; ++i) {
        const int col = bucket[b + i];
        const float w = weights[col];
        const float2 xv = ((const float2*)(x + (size_t)col * IN_DIM))[lane];
        acc.x += xv.x * w;
        acc.y += xv.y * w;
    }
    ((float2*)(readout + (size_t)node * IN_DIM))[lane] = acc;
}

// ---------------------------------------------------------------------------
// Fallback scatter (only if ws too small for binning).
// ---------------------------------------------------------------------------
__global__ __launch_bounds__(256) void scatter_kernel(
    const float* __restrict__ x, const int* __restrict__ edge_index,
    const float* __restrict__ weights, float* __restrict__ readout)
{
    const int gid = blockIdx.x * 256 + threadIdx.x;
    const int e = gid >> 5;
    const int c = gid & 31;
    if (e >= N_EDGES) return;
    const int row = edge_index[e];
    const int col = edge_index[N_EDGES + e];
    const float w = weights[col];
    const float4 xv = ((const float4*)(x + (size_t)col * IN_DIM))[c];
    float* dst = readout + (size_t)row * IN_DIM + c * 4;
    atomicAdd(dst + 0, xv.x * w);
    atomicAdd(dst + 1, xv.y * w);
    atomicAdd(dst + 2, xv.z * w);
    atomicAdd(dst + 3, xv.w * w);
}

// ---------------------------------------------------------------------------
// Prompt v3: one THREAD per node, scalar-register weights, all-register MLP.
// Layer1: acc16 chunks over 64 hidden; relu into h[64] (VGPRs).
// Layer2: h @ W2 chunked by 16 output cols; fused residual + store.
// In-place safe: thread reads its own out-row fully in layer1 before storing.
// ---------------------------------------------------------------------------
__global__ __launch_bounds__(256) void prompt_kernel(
    const float* __restrict__ x, float* __restrict__ out /* = readout */,
    const float* __restrict__ W1, const float* __restrict__ b1,
    const float* __restrict__ W2, const float* __restrict__ b2)
{
    const int node = blockIdx.x * 256 + threadIdx.x;
    if (node >= N_NODES) return;

    const float4* rr = (const float4*)(out + (size_t)node * IN_DIM);

    float h[HIDDEN];
    for (int jc = 0; jc < HIDDEN; jc += 16) {
        float acc[16];
#pragma unroll
        for (int jj = 0; jj < 16; ++jj) acc[jj] = b1[jc + jj];
        for (int k4 = 0; k4 < IN_DIM / 4; ++k4) {
            const float4 a = rr[k4];
#pragma unroll
            for (int jj = 0; jj < 16; ++jj) {
                acc[jj] += a.x * W1[(4 * k4 + 0) * HIDDEN + jc + jj];
                acc[jj] += a.y * W1[(4 * k4 + 1) * HIDDEN + jc + jj];
                acc[jj] += a.z * W1[(4 * k4 + 2) * HIDDEN + jc + jj];
                acc[jj] += a.w * W1[(4 * k4 + 3) * HIDDEN + jc + jj];
            }
        }
#pragma unroll
        for (int jj = 0; jj < 16; ++jj)
            h[jc + jj] = fmaxf(acc[jj], 0.f);
    }

    const float4* xr4 = (const float4*)(x + (size_t)node * IN_DIM);
    float4* or4 = (float4*)(out + (size_t)node * IN_DIM);

    for (int jc = 0; jc < IN_DIM; jc += 16) {
        float acc[16];
#pragma unroll
        for (int jj = 0; jj < 16; ++jj) acc[jj] = b2[jc + jj];
#pragma unroll 4
        for (int k2 = 0; k2 < HIDDEN; ++k2) {
            const float hk = h[k2];
#pragma unroll
            for (int jj = 0; jj < 16; ++jj)
                acc[jj] += hk * W2[k2 * IN_DIM + jc + jj];
        }
#pragma unroll
        for (int q = 0; q < 4; ++q) {
            const float4 xv = xr4[jc / 4 + q];
            float4 o;
            o.x = xv.x + acc[4 * q + 0];
            o.y = xv.y + acc[4 * q + 1];
            o.z = xv.z + acc[4 * q + 2];
            o.w = xv.w + acc[4 * q + 3];
            or4[jc / 4 + q] = o;
        }
    }
}

// ---------------------------------------------------------------------------
extern "C" void kernel_launch(void* const* d_in, const int* in_sizes, int n_in,
                              void* d_out, int out_size, void* d_ws, size_t ws_size,
                              hipStream_t stream)
{
    const float* x          = (const float*)d_in[0];
    const int*   edge_index = (const int*)d_in[1];   // int32 (JAX x64 disabled)
    const float* W_sim      = (const float*)d_in[2];
    const float* b_sim      = (const float*)d_in[3];
    const float* w_vec      = (const float*)d_in[4];
    const float* b_vec      = (const float*)d_in[5];
    const float* W1         = (const float*)d_in[6];
    const float* b1         = (const float*)d_in[7];
    const float* W2         = (const float*)d_in[8];
    const float* b2         = (const float*)d_in[9];

    float* out = (float*)d_out;
    float* wsf = (float*)d_ws;
    int*   wsi = (int*)d_ws;

    float* weights = wsf + WS_WEIGHTS;

    gate_kernel<<<(N_NODES + 255) / 256, 256, 0, stream>>>(x, W_sim, b_sim, w_vec, b_vec, weights);

    if (ws_size >= (size_t)WS_TOTAL * 4) {
        int* counts  = wsi + WS_COUNTS;
        int* cursor  = wsi + WS_CURSOR;
        int* counter = wsi + WS_COUNTER;
        int* base    = wsi + WS_BASE;
        int* bucket  = wsi + WS_BUCKET;

        const int nz = WS_BASE - WS_COUNTS;  // counts+cursor+counter contiguous
        zero_int_kernel<<<(nz + 255) / 256, 256, 0, stream>>>(wsi + WS_COUNTS, nz);

        hist_kernel<<<(N_EDGES + 255) / 256, 256, 0, stream>>>(edge_index, counts);
        alloc_kernel<<<(N_NODES + 255) / 256, 256, 0, stream>>>(counts, base, counter);
        fill_kernel<<<(N_EDGES + 255) / 256, 256, 0, stream>>>(edge_index, base, cursor, bucket);
        gather_kernel<<<N_NODES / 4, 256, 0, stream>>>(x, weights, counts, base, bucket, out);
    } else {
        const int n4 = N_NODES * IN_DIM / 4;
        zero_f4_kernel<<<(n4 + 255) / 256, 256, 0, stream>>>((float4*)out, n4);
        scatter_kernel<<<(N_EDGES * 32) / 256, 256, 0, stream>>>(x, edge_index, weights, out);
    }

    prompt_kernel<<<(N_NODES + 255) / 256, 256, 0, stream>>>(x, out, W1, b1, W2, b2);
}

// Round 5
// 593.592 us; speedup vs baseline: 5.6506x; 1.1212x over previous
//
#include <hip/hip_runtime.h>
#include <math.h>

#define N_NODES 100000
#define IN_DIM  128
#define HIDDEN  64
#define N_EDGES 1600000

// ---------------------------------------------------------------------------
// Workspace layout (4-byte units):
//   [0,       100000)   weights  (float)  per-node gate
//   [100000,  200000)   counts   (int)    per-node in-degree
//   [200000,  300000)   cursor   (int)    per-node fill cursor
//   [300000,  300016)   counter  (int)    global bump allocator
//   [300016,  400016)   base     (int)    per-node segment base in bucket
//   [400016, 2000016)   bucket   (int)    edge source (col) grouped by row
// ---------------------------------------------------------------------------
#define WS_WEIGHTS 0
#define WS_COUNTS  100000
#define WS_CURSOR  200000
#define WS_COUNTER 300000
#define WS_BASE    300016
#define WS_BUCKET  400016
#define WS_TOTAL   2000016

__global__ __launch_bounds__(256) void zero_int_kernel(int* __restrict__ p, int n)
{
    const int i = blockIdx.x * 256 + threadIdx.x;
    if (i < n) p[i] = 0;
}

__global__ __launch_bounds__(256) void zero_f4_kernel(float4* __restrict__ p, int n4)
{
    const int i = blockIdx.x * 256 + threadIdx.x;
    if (i < n4) p[i] = make_float4(0.f, 0.f, 0.f, 0.f);
}

// ---------------------------------------------------------------------------
// Gate: one THREAD per node; weight addresses are lane-invariant -> s_load,
// FMAs carry the weight as the SGPR operand. No arrays with dynamic indices.
// ---------------------------------------------------------------------------
__global__ __launch_bounds__(256) void gate_kernel(
    const float* __restrict__ x, const float* __restrict__ W_sim,
    const float* __restrict__ b_sim, const float* __restrict__ w_vec,
    const float* __restrict__ b_vec, float* __restrict__ weights)
{
    const int node = blockIdx.x * 256 + threadIdx.x;
    if (node >= N_NODES) return;
    const float4* xr = (const float4*)(x + (size_t)node * IN_DIM);

    float g = 0.f;
#pragma unroll
    for (int jc = 0; jc < HIDDEN; jc += 16) {
        float acc[16];
#pragma unroll
        for (int jj = 0; jj < 16; ++jj) acc[jj] = b_sim[jc + jj];
        for (int k4 = 0; k4 < IN_DIM / 4; ++k4) {
            const float4 a = xr[k4];
#pragma unroll
            for (int jj = 0; jj < 16; ++jj) {
                acc[jj] += a.x * W_sim[(4 * k4 + 0) * HIDDEN + jc + jj];
                acc[jj] += a.y * W_sim[(4 * k4 + 1) * HIDDEN + jc + jj];
                acc[jj] += a.z * W_sim[(4 * k4 + 2) * HIDDEN + jc + jj];
                acc[jj] += a.w * W_sim[(4 * k4 + 3) * HIDDEN + jc + jj];
            }
        }
#pragma unroll
        for (int jj = 0; jj < 16; ++jj)
            g += tanhf(acc[jj]) * w_vec[jc + jj];
    }
    weights[node] = 1.f / (1.f + expf(-(g + b_vec[0])));
}

// ---------------------------------------------------------------------------
// Binning: histogram -> segment alloc -> bucket fill.
// ---------------------------------------------------------------------------
__global__ __launch_bounds__(256) void hist_kernel(
    const int* __restrict__ edge_index, int* __restrict__ counts)
{
    const int e = blockIdx.x * 256 + threadIdx.x;
    if (e < N_EDGES) atomicAdd(&counts[edge_index[e]], 1);
}

__global__ __launch_bounds__(256) void alloc_kernel(
    const int* __restrict__ counts, int* __restrict__ base, int* __restrict__ counter)
{
    const int node = blockIdx.x * 256 + threadIdx.x;
    const int lane = threadIdx.x & 63;
    const int c = (node < N_NODES) ? counts[node] : 0;

    int incl = c;
#pragma unroll
    for (int off = 1; off < 64; off <<= 1) {
        int v = __shfl_up(incl, off, 64);
        if (lane >= off) incl += v;
    }
    const int excl = incl - c;
    int wbase = 0;
    if (lane == 63) wbase = atomicAdd(counter, incl);
    wbase = __shfl(wbase, 63, 64);

    if (node < N_NODES) base[node] = wbase + excl;
}

__global__ __launch_bounds__(256) void fill_kernel(
    const int* __restrict__ edge_index, const int* __restrict__ base,
    int* __restrict__ cursor, int* __restrict__ bucket)
{
    const int e = blockIdx.x * 256 + threadIdx.x;
    if (e >= N_EDGES) return;
    const int row = edge_index[e];
    const int col = edge_index[N_EDGES + e];
    const int pos = atomicAdd(&cursor[row], 1);
    bucket[base[row] + pos] = col;
}

// ---------------------------------------------------------------------------
// Gather v2: one wave per node, HALF-WAVE edge pairing.
// Lanes 0-31 process even bucket slots, lanes 32-63 odd slots; each lane
// holds float4 (32 lanes x 16B = full 512B row) -> every VMEM instruction
// moves 1KB (two source rows), halving loop trips and doubling MLP chains
// in flight. Cross-half shuffle-combine at the end; half 0 stores the row.
// ---------------------------------------------------------------------------
__global__ __launch_bounds__(256) void gather_kernel(
    const float* __restrict__ x, const float* __restrict__ weights,
    const int* __restrict__ counts, const int* __restrict__ base,
    const int* __restrict__ bucket, float* __restrict__ readout)
{
    const int wave = threadIdx.x >> 6;
    const int lane = threadIdx.x & 63;
    const int half = lane >> 5;       // 0: even slots, 1: odd slots
    const int l32  = lane & 31;
    const int node = blockIdx.x * 4 + wave;
    if (node >= N_NODES) return;

    const int m = counts[node];
    const int b = base[node];

    float4 acc = make_float4(0.f, 0.f, 0.f, 0.f);
    for (int i = half; i < m; i += 2) {
        const int col = bucket[b + i];          // uniform per half-wave
        const float w = weights[col];
        const float4 xv = ((const float4*)(x + (size_t)col * IN_DIM))[l32];
        acc.x += xv.x * w;
        acc.y += xv.y * w;
        acc.z += xv.z * w;
        acc.w += xv.w * w;
    }
    // combine the two halves (partner lane = lane ^ 32)
    acc.x += __shfl(acc.x, lane ^ 32, 64);
    acc.y += __shfl(acc.y, lane ^ 32, 64);
    acc.z += __shfl(acc.z, lane ^ 32, 64);
    acc.w += __shfl(acc.w, lane ^ 32, 64);

    if (half == 0)
        ((float4*)(readout + (size_t)node * IN_DIM))[l32] = acc;
}

// ---------------------------------------------------------------------------
// Fallback scatter (only if ws too small for binning).
// ---------------------------------------------------------------------------
__global__ __launch_bounds__(256) void scatter_kernel(
    const float* __restrict__ x, const int* __restrict__ edge_index,
    const float* __restrict__ weights, float* __restrict__ readout)
{
    const int gid = blockIdx.x * 256 + threadIdx.x;
    const int e = gid >> 5;
    const int c = gid & 31;
    if (e >= N_EDGES) return;
    const int row = edge_index[e];
    const int col = edge_index[N_EDGES + e];
    const float w = weights[col];
    const float4 xv = ((const float4*)(x + (size_t)col * IN_DIM))[c];
    float* dst = readout + (size_t)row * IN_DIM + c * 4;
    atomicAdd(dst + 0, xv.x * w);
    atomicAdd(dst + 1, xv.y * w);
    atomicAdd(dst + 2, xv.z * w);
    atomicAdd(dst + 3, xv.w * w);
}

// ---------------------------------------------------------------------------
// Prompt v4: one THREAD per node. ALL loops that index h[] are fully
// unrolled so h/acc stay in VGPRs (R4's VGPR_Count=20 + VALUBusy 0.6%
// showed dynamic indexing demoted them to scratch).
// ---------------------------------------------------------------------------
__global__ __launch_bounds__(256) void prompt_kernel(
    const float* __restrict__ x, float* __restrict__ out /* = readout */,
    const float* __restrict__ W1, const float* __restrict__ b1,
    const float* __restrict__ W2, const float* __restrict__ b2)
{
    const int node = blockIdx.x * 256 + threadIdx.x;
    if (node >= N_NODES) return;

    const float4* rr = (const float4*)(out + (size_t)node * IN_DIM);

    float h[HIDDEN];
#pragma unroll
    for (int jc = 0; jc < HIDDEN; jc += 16) {   // 4 chunks, UNROLLED
        float acc[16];
#pragma unroll
        for (int jj = 0; jj < 16; ++jj) acc[jj] = b1[jc + jj];
        for (int k4 = 0; k4 < IN_DIM / 4; ++k4) {  // row re-read from L1 per chunk
            const float4 a = rr[k4];
#pragma unroll
            for (int jj = 0; jj < 16; ++jj) {
                acc[jj] += a.x * W1[(4 * k4 + 0) * HIDDEN + jc + jj];
                acc[jj] += a.y * W1[(4 * k4 + 1) * HIDDEN + jc + jj];
                acc[jj] += a.z * W1[(4 * k4 + 2) * HIDDEN + jc + jj];
                acc[jj] += a.w * W1[(4 * k4 + 3) * HIDDEN + jc + jj];
            }
        }
#pragma unroll
        for (int jj = 0; jj < 16; ++jj)
            h[jc + jj] = fmaxf(acc[jj], 0.f);    // constant index
    }

    const float4* xr4 = (const float4*)(x + (size_t)node * IN_DIM);
    float4* or4 = (float4*)(out + (size_t)node * IN_DIM);

    for (int jc = 0; jc < IN_DIM; jc += 16) {    // rolled: code size control
        float acc[16];
#pragma unroll
        for (int jj = 0; jj < 16; ++jj) acc[jj] = b2[jc + jj];
#pragma unroll
        for (int k2 = 0; k2 < HIDDEN; ++k2) {    // FULL unroll: h[k2] constant
            const float hk = h[k2];
#pragma unroll
            for (int jj = 0; jj < 16; ++jj)
                acc[jj] += hk * W2[k2 * IN_DIM + jc + jj];
        }
#pragma unroll
        for (int q = 0; q < 4; ++q) {
            const float4 xv = xr4[jc / 4 + q];
            float4 o;
            o.x = xv.x + acc[4 * q + 0];
            o.y = xv.y + acc[4 * q + 1];
            o.z = xv.z + acc[4 * q + 2];
            o.w = xv.w + acc[4 * q + 3];
            or4[jc / 4 + q] = o;
        }
    }
}

// ---------------------------------------------------------------------------
extern "C" void kernel_launch(void* const* d_in, const int* in_sizes, int n_in,
                              void* d_out, int out_size, void* d_ws, size_t ws_size,
                              hipStream_t stream)
{
    const float* x          = (const float*)d_in[0];
    const int*   edge_index = (const int*)d_in[1];   // int32 (JAX x64 disabled)
    const float* W_sim      = (const float*)d_in[2];
    const float* b_sim      = (const float*)d_in[3];
    const float* w_vec      = (const float*)d_in[4];
    const float* b_vec      = (const float*)d_in[5];
    const float* W1         = (const float*)d_in[6];
    const float* b1         = (const float*)d_in[7];
    const float* W2         = (const float*)d_in[8];
    const float* b2         = (const float*)d_in[9];

    float* out = (float*)d_out;
    float* wsf = (float*)d_ws;
    int*   wsi = (int*)d_ws;

    float* weights = wsf + WS_WEIGHTS;

    gate_kernel<<<(N_NODES + 255) / 256, 256, 0, stream>>>(x, W_sim, b_sim, w_vec, b_vec, weights);

    if (ws_size >= (size_t)WS_TOTAL * 4) {
        int* counts  = wsi + WS_COUNTS;
        int* cursor  = wsi + WS_CURSOR;
        int* counter = wsi + WS_COUNTER;
        int* base    = wsi + WS_BASE;
        int* bucket  = wsi + WS_BUCKET;

        const int nz = WS_BASE - WS_COUNTS;  // counts+cursor+counter contiguous
        zero_int_kernel<<<(nz + 255) / 256, 256, 0, stream>>>(wsi + WS_COUNTS, nz);

        hist_kernel<<<(N_EDGES + 255) / 256, 256, 0, stream>>>(edge_index, counts);
        alloc_kernel<<<(N_NODES + 255) / 256, 256, 0, stream>>>(counts, base, counter);
        fill_kernel<<<(N_EDGES + 255) / 256, 256, 0, stream>>>(edge_index, base, cursor, bucket);
        gather_kernel<<<N_NODES / 4, 256, 0, stream>>>(x, weights, counts, base, bucket, out);
    } else {
        const int n4 = N_NODES * IN_DIM / 4;
        zero_f4_kernel<<<(n4 + 255) / 256, 256, 0, stream>>>((float4*)out, n4);
        scatter_kernel<<<(N_EDGES * 32) / 256, 256, 0, stream>>>(x, edge_index, weights, out);
    }

    prompt_kernel<<<(N_NODES + 255) / 256, 256, 0, stream>>>(x, out, W1, b1, W2, b2);
}